// Round 1
// baseline (3411.842 us; speedup 1.0000x reference)
//
#include <hip/hip_runtime.h>
#include <hip/hip_bf16.h>

// Shapes: B=128, L=512, D=13, H=128, G=4H=512.
typedef __attribute__((ext_vector_type(8))) short bf16x8;
typedef __attribute__((ext_vector_type(4))) float f32x4;

__device__ __forceinline__ float bfbits(unsigned short u) {
  unsigned int v = ((unsigned int)u) << 16;
  return __uint_as_float(v);
}
__device__ __forceinline__ float sigf(float x) { return 1.f / (1.f + __expf(-x)); }
__device__ __forceinline__ float tanhf_(float x) {
  x = fminf(15.f, fmaxf(-15.f, x));
  float t = __expf(2.f * x);
  return (t - 1.f) / (t + 1.f);
}

// ---------------------------------------------------------------------------
// Weight prep: Whh -> transposed fp32 whht[lay][d][k][j] (exact, coalesced scan
// loads); Wih(21/31/32) -> bf16 for MFMA; bsum = bih + bhh (fp32).
// ---------------------------------------------------------------------------
__global__ __launch_bounds__(256) void wconv(
    const float* whh0, const float* whh1, const float* whh2, const float* whh3, const float* whh4,
    const float* wi21, const float* wi31, const float* wi32,
    const float* bi0, const float* bh0, const float* bi1, const float* bh1,
    const float* bi2, const float* bh2, const float* bi3, const float* bh3,
    const float* bi4, const float* bh4,
    float* whht, __hip_bfloat16* wihbf, float* bsum)
{
  int tid = blockIdx.x * 256 + threadIdx.x;
  if (tid < 5 * 131072) {                       // whht: [5][2][128][512]
    int lay = tid / 131072, r = tid % 131072;
    const float* src = lay == 0 ? whh0 : lay == 1 ? whh1 : lay == 2 ? whh2 : lay == 3 ? whh3 : whh4;
    int d = r >> 16;          // 65536 per dir
    int k = (r >> 9) & 127;
    int j = r & 511;
    whht[tid] = src[((size_t)d * 512 + j) * 128 + k];   // Whh[d][j][k]
    return;
  }
  int t2 = tid - 5 * 131072;
  if (t2 < 1048576) {                           // wihbf: w21 | w31 | w32
    const float* src; int idx;
    if (t2 < 262144)      { src = wi21; idx = t2; }
    else if (t2 < 786432) { src = wi31; idx = t2 - 262144; }
    else                  { src = wi32; idx = t2 - 786432; }
    wihbf[t2] = __float2bfloat16(src[idx]);
    return;
  }
  int t3 = t2 - 1048576;                        // bsum: [5][2][512]
  if (t3 < 5120) {
    int lay = t3 >> 10, idx = t3 & 1023;
    const float* bi = lay == 0 ? bi0 : lay == 1 ? bi1 : lay == 2 ? bi2 : lay == 3 ? bi3 : bi4;
    const float* bh = lay == 0 ? bh0 : lay == 1 ? bh1 : lay == 2 ? bh2 : lay == 3 ? bh3 : bh4;
    bsum[t3] = bi[idx] + bh[idx];
  }
}

// ---------------------------------------------------------------------------
// K=13 projection (layers 1 and 22): fp32 compute, bf16 store.
// xg layout: [d][b][t][512], flat index == tid.
// ---------------------------------------------------------------------------
__global__ __launch_bounds__(256) void proj13(
    const float* __restrict__ x, const float* __restrict__ wih,
    const float* __restrict__ bsum, __hip_bfloat16* __restrict__ xg)
{
  int tid = blockIdx.x * 256 + threadIdx.x;   // 2^26 threads
  int col = tid & 511;
  int bt  = (tid >> 9) & 65535;
  int d   = tid >> 25;
  const float* xp = x + (size_t)bt * 13;
  const float* wp = wih + ((size_t)d * 512 + col) * 13;
  float acc = bsum[d * 512 + col];
#pragma unroll
  for (int k = 0; k < 13; ++k) acc += xp[k] * wp[k];
  xg[tid] = __float2bfloat16(acc);
}

// ---------------------------------------------------------------------------
// bf16 MFMA projection GEMM: C[M=65536, N=512] = A[M,K] * Bw[N,K]^T + bsum.
// 128x128 tile, BK=32, 4 waves, XOR chunk swizzle (slot = chunk ^ (row&3)).
// ---------------------------------------------------------------------------
__global__ __launch_bounds__(256) void projM(
    const __hip_bfloat16* __restrict__ A, int lda, int K,
    const __hip_bfloat16* __restrict__ Bw,
    const float* __restrict__ bsum,
    __hip_bfloat16* __restrict__ out)
{
  int d = blockIdx.z;
  const __hip_bfloat16* Bp = Bw + (size_t)d * 512 * K;
  const float* bs = bsum + d * 512;
  __hip_bfloat16* op = out + (size_t)d * 65536 * 512;
  int m0 = blockIdx.y * 128, n0 = blockIdx.x * 128;
  __shared__ __align__(16) __hip_bfloat16 As[128][32];
  __shared__ __align__(16) __hip_bfloat16 Bs[128][32];
  int tid = threadIdx.x, w = tid >> 6, l = tid & 63;
  int wm = (w >> 1) * 64, wn = (w & 1) * 64;
  f32x4 acc[4][4];
#pragma unroll
  for (int mi = 0; mi < 4; ++mi)
#pragma unroll
    for (int ni = 0; ni < 4; ++ni) acc[mi][ni] = (f32x4){0.f, 0.f, 0.f, 0.f};
  int srow = tid >> 2, sc = tid & 3;
  for (int k0 = 0; k0 < K; k0 += 32) {
#pragma unroll
    for (int p = 0; p < 2; ++p) {
      int row = p * 64 + srow;
      int slot = sc ^ (row & 3);
      uint4 va = *(const uint4*)(A + (size_t)(m0 + row) * lda + k0 + sc * 8);
      *(uint4*)(&As[row][slot * 8]) = va;
      uint4 vb = *(const uint4*)(Bp + (size_t)(n0 + row) * K + k0 + sc * 8);
      *(uint4*)(&Bs[row][slot * 8]) = vb;
    }
    __syncthreads();
    bf16x8 af[4], bfr[4];
#pragma unroll
    for (int mi = 0; mi < 4; ++mi) {
      int row = wm + mi * 16 + (l & 15);
      int slot = (l >> 4) ^ (row & 3);
      af[mi] = *(const bf16x8*)(&As[row][slot * 8]);
    }
#pragma unroll
    for (int ni = 0; ni < 4; ++ni) {
      int row = wn + ni * 16 + (l & 15);
      int slot = (l >> 4) ^ (row & 3);
      bfr[ni] = *(const bf16x8*)(&Bs[row][slot * 8]);
    }
#pragma unroll
    for (int mi = 0; mi < 4; ++mi)
#pragma unroll
      for (int ni = 0; ni < 4; ++ni)
        acc[mi][ni] = __builtin_amdgcn_mfma_f32_16x16x32_bf16(af[mi], bfr[ni], acc[mi][ni], 0, 0, 0);
    __syncthreads();
  }
#pragma unroll
  for (int ni = 0; ni < 4; ++ni) {
    int col = n0 + wn + ni * 16 + (l & 15);
    float bsv = bs[col];
#pragma unroll
    for (int mi = 0; mi < 4; ++mi) {
#pragma unroll
      for (int q = 0; q < 4; ++q) {
        int row = m0 + wm + mi * 16 + (l >> 4) * 4 + q;
        op[(size_t)row * 512 + col] = __float2bfloat16(acc[mi][ni][q] + bsv);
      }
    }
  }
}

// ---------------------------------------------------------------------------
// LSTM scan: block = (batch row b, direction d). 512 threads, thread j = gate j.
// Whh row (fp32, exact) in 128 VGPRs via transposed coalesced load. h broadcast
// through LDS. xg prefetched one step ahead. Optional L-maxpool epilogue.
// ---------------------------------------------------------------------------
__global__ __launch_bounds__(512) void lstm_scan(
    const __hip_bfloat16* __restrict__ xg,   // [2][B][L][512] this layer
    const float* __restrict__ whht,          // [2][128][512] this layer
    __hip_bfloat16* __restrict__ yout, int ycols, int ycoloff,
    float* __restrict__ y3out, int y3off)
{
  int b = blockIdx.x, d = blockIdx.y, j = threadIdx.x;
  __shared__ __align__(16) float h_lds[128];
  __shared__ float g_lds[512];
  float wv[128];
  const float* wp = whht + (size_t)d * 65536 + j;
#pragma unroll
  for (int k = 0; k < 128; ++k) wv[k] = wp[(size_t)k * 512];
  if (j < 128) h_lds[j] = 0.f;
  float c = 0.f, mreg = -1e30f;
  const __hip_bfloat16* xp = xg + ((size_t)d * 128 + b) * 262144;
  __hip_bfloat16* yp = yout ? (yout + (size_t)b * 512 * ycols + ycoloff + d * 128) : (__hip_bfloat16*)0;
  __syncthreads();
  unsigned short xraw = *(const unsigned short*)(xp + (size_t)(d ? 511 : 0) * 512 + j);
  for (int t = 0; t < 512; ++t) {
    int tn = (t + 1 < 512) ? t + 1 : 511;
    int ttn = d ? 511 - tn : tn;
    unsigned short xnext = *(const unsigned short*)(xp + (size_t)ttn * 512 + j);  // prefetch
    float accv = bfbits(xraw);
    const float4* h4 = (const float4*)h_lds;
#pragma unroll
    for (int kk = 0; kk < 32; ++kk) {
      float4 hv = h4[kk];
      accv += hv.x * wv[4 * kk] + hv.y * wv[4 * kk + 1] + hv.z * wv[4 * kk + 2] + hv.w * wv[4 * kk + 3];
    }
    g_lds[j] = accv;
    __syncthreads();
    int tt = d ? 511 - t : t;
    if (j < 128) {
      float gi = g_lds[j], gf = g_lds[j + 128], gg = g_lds[j + 256], go = g_lds[j + 384];
      c = sigf(gf) * c + sigf(gi) * tanhf_(gg);
      float h = sigf(go) * tanhf_(c);
      h_lds[j] = h;
      if (yout) yp[(size_t)tt * ycols + j] = __float2bfloat16(h);
      else mreg = fmaxf(mreg, h);
    }
    __syncthreads();
    xraw = xnext;
  }
  if (!yout && j < 128) y3out[(size_t)b * 512 + y3off + d * 128 + j] = mreg;
}

// ---------------------------------------------------------------------------
// Head: y4 = selu(y3 @ l4w^T + l4b); out = sigmoid(y4 @ fcw^T + fcb).
// ---------------------------------------------------------------------------
__global__ __launch_bounds__(256) void head(
    const float* __restrict__ y3, const float* __restrict__ l4w,
    const float* __restrict__ l4b, const float* __restrict__ fcw,
    const float* __restrict__ fcb, float* __restrict__ outp)
{
  int b = blockIdx.x, t = threadIdx.x;
  __shared__ float row[512];
  __shared__ float y4[128];
  row[t] = y3[(size_t)b * 512 + t];
  row[t + 256] = y3[(size_t)b * 512 + t + 256];
  __syncthreads();
  if (t < 128) {
    float acc = l4b[t];
    const float* wr = l4w + (size_t)t * 512;
    for (int k = 0; k < 512; ++k) acc += row[k] * wr[k];
    const float scale = 1.0507009873554804934193349852946f;
    const float alpha = 1.6732632423543772848170429916717f;
    y4[t] = acc > 0.f ? scale * acc : scale * alpha * (__expf(acc) - 1.f);
  }
  __syncthreads();
  if (t < 2) {
    float acc = fcb[t];
    const float* wr = fcw + (size_t)t * 128;
    for (int k = 0; k < 128; ++k) acc += y4[k] * wr[k];
    outp[b * 2 + t] = 1.f / (1.f + __expf(-acc));
  }
}

extern "C" void kernel_launch(void* const* d_in, const int* in_sizes, int n_in,
                              void* d_out, int out_size, void* d_ws, size_t ws_size,
                              hipStream_t stream) {
  (void)in_sizes; (void)n_in; (void)out_size; (void)ws_size;
  const float* x     = (const float*)d_in[0];
  const float* Wih1  = (const float*)d_in[1];
  const float* Whh1  = (const float*)d_in[2];
  const float* bih1  = (const float*)d_in[3];
  const float* bhh1  = (const float*)d_in[4];
  const float* Wih21 = (const float*)d_in[5];
  const float* Whh21 = (const float*)d_in[6];
  const float* bih21 = (const float*)d_in[7];
  const float* bhh21 = (const float*)d_in[8];
  const float* Wih22 = (const float*)d_in[9];
  const float* Whh22 = (const float*)d_in[10];
  const float* bih22 = (const float*)d_in[11];
  const float* bhh22 = (const float*)d_in[12];
  const float* Wih31 = (const float*)d_in[13];
  const float* Whh31 = (const float*)d_in[14];
  const float* bih31 = (const float*)d_in[15];
  const float* bhh31 = (const float*)d_in[16];
  const float* Wih32 = (const float*)d_in[17];
  const float* Whh32 = (const float*)d_in[18];
  const float* bih32 = (const float*)d_in[19];
  const float* bhh32 = (const float*)d_in[20];
  const float* l4w   = (const float*)d_in[21];
  const float* l4b   = (const float*)d_in[22];
  const float* fcw   = (const float*)d_in[23];
  const float* fcb   = (const float*)d_in[24];

  char* ws = (char*)d_ws;
  __hip_bfloat16* xg    = (__hip_bfloat16*)(ws);               // 134217728 B
  __hip_bfloat16* y1    = (__hip_bfloat16*)(ws + 134217728);   // 33554432 B
  __hip_bfloat16* y2    = (__hip_bfloat16*)(ws + 167772160);   // 67108864 B
  float*          y3    = (float*)(ws + 234881024);            // 262144 B
  __hip_bfloat16* wihbf = (__hip_bfloat16*)(ws + 235143168);   // 2097152 B
  float*          bsum  = (float*)(ws + 237240320);            // 20480 B
  float*          whht  = (float*)(ws + 237260800);            // 2621440 B -> total ~228.8 MB

  wconv<<<6676, 256, 0, stream>>>(Whh1, Whh21, Whh22, Whh31, Whh32,
                                  Wih21, Wih31, Wih32,
                                  bih1, bhh1, bih21, bhh21, bih22, bhh22,
                                  bih31, bhh31, bih32, bhh32,
                                  whht, wihbf, bsum);
  // layer 1 (in = x)
  proj13<<<262144, 256, 0, stream>>>(x, Wih1, bsum + 0 * 1024, xg);
  lstm_scan<<<dim3(128, 2), 512, 0, stream>>>(xg, whht + 0 * 131072, y1, 256, 0, nullptr, 0);
  // layer 22 (in = x) -> y2 cols 256..511
  proj13<<<262144, 256, 0, stream>>>(x, Wih22, bsum + 2 * 1024, xg);
  lstm_scan<<<dim3(128, 2), 512, 0, stream>>>(xg, whht + 2 * 131072, y2, 512, 256, nullptr, 0);
  // layer 21 (in = y1) -> y2 cols 0..255
  projM<<<dim3(4, 512, 2), 256, 0, stream>>>(y1, 256, 256, wihbf + 0, bsum + 1 * 1024, xg);
  lstm_scan<<<dim3(128, 2), 512, 0, stream>>>(xg, whht + 1 * 131072, y2, 512, 0, nullptr, 0);
  // layer 31 (in = y2, K=512) -> y3 cols 0..255 (maxpool)
  projM<<<dim3(4, 512, 2), 256, 0, stream>>>(y2, 512, 512, wihbf + 262144, bsum + 3 * 1024, xg);
  lstm_scan<<<dim3(128, 2), 512, 0, stream>>>(xg, whht + 3 * 131072, nullptr, 0, 0, y3, 0);
  // layer 32 (in = y21 = y2 cols 0..255, K=256) -> y3 cols 256..511 (maxpool)
  projM<<<dim3(4, 512, 2), 256, 0, stream>>>(y2, 512, 256, wihbf + 786432, bsum + 4 * 1024, xg);
  lstm_scan<<<dim3(128, 2), 512, 0, stream>>>(xg, whht + 4 * 131072, nullptr, 0, 0, y3, 256);
  // head
  head<<<128, 256, 0, stream>>>(y3, l4w, l4b, fcw, fcb, (float*)d_out);
}

// Round 2
// 3257.725 us; speedup vs baseline: 1.0473x; 1.0473x over previous
//
#include <hip/hip_runtime.h>
#include <hip/hip_bf16.h>

// Shapes: B=128, L=512, D=13, H=128, G=4H=512.
typedef __attribute__((ext_vector_type(8))) short bf16x8;
typedef __attribute__((ext_vector_type(4))) float f32x4;

__device__ __forceinline__ float bfbits(unsigned short u) {
  unsigned int v = ((unsigned int)u) << 16;
  return __uint_as_float(v);
}
__device__ __forceinline__ float sigf(float x) { return 1.f / (1.f + __expf(-x)); }
__device__ __forceinline__ float tanhf_(float x) {
  x = fminf(15.f, fmaxf(-15.f, x));
  float t = __expf(2.f * x);
  return (t - 1.f) / (t + 1.f);
}

// ---------------------------------------------------------------------------
// Weight prep: Whh -> transposed fp32 whht[lay][d][k][j]; Wih(21/31/32) -> bf16
// for MFMA; bsum = bih + bhh (fp32); Wih(1/22) -> transposed fp32 [lay][d][k][j]
// for the fused-D13 scan.
// ---------------------------------------------------------------------------
__global__ __launch_bounds__(256) void wconv(
    const float* whh0, const float* whh1, const float* whh2, const float* whh3, const float* whh4,
    const float* wi21, const float* wi31, const float* wi32,
    const float* wi1, const float* wi22,
    const float* bi0, const float* bh0, const float* bi1, const float* bh1,
    const float* bi2, const float* bh2, const float* bi3, const float* bh3,
    const float* bi4, const float* bh4,
    float* whht, __hip_bfloat16* wihbf, float* bsum, float* wihT13)
{
  int tid = blockIdx.x * 256 + threadIdx.x;
  if (tid < 5 * 131072) {                       // whht: [5][2][128][512]
    int lay = tid / 131072, r = tid % 131072;
    const float* src = lay == 0 ? whh0 : lay == 1 ? whh1 : lay == 2 ? whh2 : lay == 3 ? whh3 : whh4;
    int d = r >> 16;
    int k = (r >> 9) & 127;
    int j = r & 511;
    whht[tid] = src[((size_t)d * 512 + j) * 128 + k];   // Whh[d][j][k]
    return;
  }
  int t2 = tid - 5 * 131072;
  if (t2 < 1048576) {                           // wihbf: w21 | w31 | w32 (bf16)
    const float* src; int idx;
    if (t2 < 262144)      { src = wi21; idx = t2; }
    else if (t2 < 786432) { src = wi31; idx = t2 - 262144; }
    else                  { src = wi32; idx = t2 - 786432; }
    wihbf[t2] = __float2bfloat16(src[idx]);
    return;
  }
  int t3 = t2 - 1048576;
  if (t3 < 5120) {                              // bsum: [5][2][512]
    int lay = t3 >> 10, idx = t3 & 1023;
    const float* bi = lay == 0 ? bi0 : lay == 1 ? bi1 : lay == 2 ? bi2 : lay == 3 ? bi3 : bi4;
    const float* bh = lay == 0 ? bh0 : lay == 1 ? bh1 : lay == 2 ? bh2 : lay == 3 ? bh3 : bh4;
    bsum[t3] = bi[idx] + bh[idx];
    return;
  }
  int t4 = t3 - 5120;
  if (t4 < 26624) {                             // wihT13: [2][2][13][512]
    int lay = t4 / 13312, r = t4 % 13312;
    const float* src = lay == 0 ? wi1 : wi22;
    int d = r / 6656, rr = r % 6656;
    int k = rr / 512, j = rr % 512;
    wihT13[t4] = src[((size_t)d * 512 + j) * 13 + k];
  }
}

// ---------------------------------------------------------------------------
// bf16 MFMA projection GEMM: C[M=65536, N=512] = A[M,K] * Bw[N,K]^T + bsum.
// 128x128 tile, BK=32, 4 waves, XOR chunk swizzle.
// ---------------------------------------------------------------------------
__global__ __launch_bounds__(256) void projM(
    const __hip_bfloat16* __restrict__ A, int lda, int K,
    const __hip_bfloat16* __restrict__ Bw,
    const float* __restrict__ bsum,
    __hip_bfloat16* __restrict__ out)
{
  int d = blockIdx.z;
  const __hip_bfloat16* Bp = Bw + (size_t)d * 512 * K;
  const float* bs = bsum + d * 512;
  __hip_bfloat16* op = out + (size_t)d * 65536 * 512;
  int m0 = blockIdx.y * 128, n0 = blockIdx.x * 128;
  __shared__ __align__(16) __hip_bfloat16 As[128][32];
  __shared__ __align__(16) __hip_bfloat16 Bs[128][32];
  int tid = threadIdx.x, w = tid >> 6, l = tid & 63;
  int wm = (w >> 1) * 64, wn = (w & 1) * 64;
  f32x4 acc[4][4];
#pragma unroll
  for (int mi = 0; mi < 4; ++mi)
#pragma unroll
    for (int ni = 0; ni < 4; ++ni) acc[mi][ni] = (f32x4){0.f, 0.f, 0.f, 0.f};
  int srow = tid >> 2, sc = tid & 3;
  for (int k0 = 0; k0 < K; k0 += 32) {
#pragma unroll
    for (int p = 0; p < 2; ++p) {
      int row = p * 64 + srow;
      int slot = sc ^ (row & 3);
      uint4 va = *(const uint4*)(A + (size_t)(m0 + row) * lda + k0 + sc * 8);
      *(uint4*)(&As[row][slot * 8]) = va;
      uint4 vb = *(const uint4*)(Bp + (size_t)(n0 + row) * K + k0 + sc * 8);
      *(uint4*)(&Bs[row][slot * 8]) = vb;
    }
    __syncthreads();
    bf16x8 af[4], bfr[4];
#pragma unroll
    for (int mi = 0; mi < 4; ++mi) {
      int row = wm + mi * 16 + (l & 15);
      int slot = (l >> 4) ^ (row & 3);
      af[mi] = *(const bf16x8*)(&As[row][slot * 8]);
    }
#pragma unroll
    for (int ni = 0; ni < 4; ++ni) {
      int row = wn + ni * 16 + (l & 15);
      int slot = (l >> 4) ^ (row & 3);
      bfr[ni] = *(const bf16x8*)(&Bs[row][slot * 8]);
    }
#pragma unroll
    for (int mi = 0; mi < 4; ++mi)
#pragma unroll
      for (int ni = 0; ni < 4; ++ni)
        acc[mi][ni] = __builtin_amdgcn_mfma_f32_16x16x32_bf16(af[mi], bfr[ni], acc[mi][ni], 0, 0, 0);
    __syncthreads();
  }
#pragma unroll
  for (int ni = 0; ni < 4; ++ni) {
    int col = n0 + wn + ni * 16 + (l & 15);
    float bsv = bs[col];
#pragma unroll
    for (int mi = 0; mi < 4; ++mi) {
#pragma unroll
      for (int q = 0; q < 4; ++q) {
        int row = m0 + wm + mi * 16 + (l >> 4) * 4 + q;
        op[(size_t)row * 512 + col] = __float2bfloat16(acc[mi][ni][q] + bsv);
      }
    }
  }
}

// ---------------------------------------------------------------------------
// LSTM scan v2: block = (b, d), 1024 threads = (half, gate j). Each thread does
// a 64-FMA half-dot (4 independent acc chains); partials meet in LDS. Cell
// update on threads 0..127 (exact fp32 c/h). Optional fused D=13 input proj
// (x staged in LDS, no xg buffer). 16 waves/block -> 4 waves/SIMD.
// ---------------------------------------------------------------------------
struct ScanIO {
  const __hip_bfloat16* xg;   // [2][B][L][512], used when !FUSE13
  const float* x;             // [B][L][13], used when FUSE13
  const float* wihT;          // [2][13][512], used when FUSE13
  const float* whht;          // [2][128][512]
  const float* bs;            // [2][512]
  __hip_bfloat16* yout; int ycols; int ycoloff;
  float* y3out; int y3off;
};

template<bool FUSE13>
__global__ __launch_bounds__(1024, 4) void lstm_scan2(ScanIO io)
{
  int b = blockIdx.x, d = blockIdx.y;
  int tid = threadIdx.x;
  int half = tid >> 9, j = tid & 511;
  __shared__ __align__(16) float h_lds[128];
  __shared__ float p_lds[2][512];
  __shared__ float x_lds[FUSE13 ? 6656 : 4];

  float wv[64];
  {
    const float* wp = io.whht + (size_t)d * 65536 + (size_t)(half * 64) * 512 + j;
#pragma unroll
    for (int k = 0; k < 64; ++k) wv[k] = wp[(size_t)k * 512];
  }
  float wx[13];
  if (FUSE13) {
    const float* q = io.wihT + d * 6656 + j;
#pragma unroll
    for (int k = 0; k < 13; ++k) wx[k] = q[k * 512];
    for (int i = tid; i < 6656; i += 1024) x_lds[i] = io.x[(size_t)b * 6656 + i];
  }
  float bias = (half == 0) ? io.bs[d * 512 + j] : 0.f;
  if (tid < 128) h_lds[tid] = 0.f;
  float c = 0.f, mreg = -1e30f;
  __hip_bfloat16* yp = io.yout ? io.yout + (size_t)b * 512 * io.ycols + io.ycoloff + d * 128 : (__hip_bfloat16*)0;
  const __hip_bfloat16* xp = FUSE13 ? (const __hip_bfloat16*)0 : io.xg + ((size_t)d * 128 + b) * 262144;
  __syncthreads();
  unsigned short xraw = 0;
  if (!FUSE13 && half == 0) xraw = *(const unsigned short*)(xp + (size_t)(d ? 511 : 0) * 512 + j);
  for (int t = 0; t < 512; ++t) {
    int tt = d ? 511 - t : t;
    unsigned short xnext = 0;
    if (!FUSE13 && half == 0) {
      int tn = (t + 1 < 512) ? t + 1 : 511;
      int ttn = d ? 511 - tn : tn;
      xnext = *(const unsigned short*)(xp + (size_t)ttn * 512 + j);  // prefetch
    }
    float a0 = bias, a1 = 0.f, a2 = 0.f, a3 = 0.f;
    if (!FUSE13) {
      if (half == 0) a0 += bfbits(xraw);
    } else if (half == 0) {
      const float* xr = &x_lds[tt * 13];
      a0 += xr[0] * wx[0] + xr[4] * wx[4] + xr[8] * wx[8] + xr[12] * wx[12];
      a1 += xr[1] * wx[1] + xr[5] * wx[5] + xr[9] * wx[9];
      a2 += xr[2] * wx[2] + xr[6] * wx[6] + xr[10] * wx[10];
      a3 += xr[3] * wx[3] + xr[7] * wx[7] + xr[11] * wx[11];
    }
    const float4* h4 = ((const float4*)h_lds) + half * 16;
#pragma unroll
    for (int kk = 0; kk < 16; kk += 4) {
      float4 h0 = h4[kk], h1 = h4[kk + 1], h2 = h4[kk + 2], h3 = h4[kk + 3];
      a0 += h0.x * wv[4 * kk +  0] + h0.y * wv[4 * kk +  1] + h0.z * wv[4 * kk +  2] + h0.w * wv[4 * kk +  3];
      a1 += h1.x * wv[4 * kk +  4] + h1.y * wv[4 * kk +  5] + h1.z * wv[4 * kk +  6] + h1.w * wv[4 * kk +  7];
      a2 += h2.x * wv[4 * kk +  8] + h2.y * wv[4 * kk +  9] + h2.z * wv[4 * kk + 10] + h2.w * wv[4 * kk + 11];
      a3 += h3.x * wv[4 * kk + 12] + h3.y * wv[4 * kk + 13] + h3.z * wv[4 * kk + 14] + h3.w * wv[4 * kk + 15];
    }
    p_lds[half][j] = (a0 + a1) + (a2 + a3);
    __syncthreads();
    if (tid < 128) {
      float gi = p_lds[0][tid]       + p_lds[1][tid];
      float gf = p_lds[0][tid + 128] + p_lds[1][tid + 128];
      float gg = p_lds[0][tid + 256] + p_lds[1][tid + 256];
      float go = p_lds[0][tid + 384] + p_lds[1][tid + 384];
      c = sigf(gf) * c + sigf(gi) * tanhf_(gg);
      float h = sigf(go) * tanhf_(c);
      h_lds[tid] = h;
      if (yp) yp[(size_t)tt * io.ycols + tid] = __float2bfloat16(h);
      else mreg = fmaxf(mreg, h);
    }
    __syncthreads();
    xraw = xnext;
  }
  if (!yp && tid < 128) io.y3out[(size_t)b * 512 + io.y3off + d * 128 + tid] = mreg;
}

// ---------------------------------------------------------------------------
// Head: y4 = selu(y3 @ l4w^T + l4b); out = sigmoid(y4 @ fcw^T + fcb).
// ---------------------------------------------------------------------------
__global__ __launch_bounds__(256) void head(
    const float* __restrict__ y3, const float* __restrict__ l4w,
    const float* __restrict__ l4b, const float* __restrict__ fcw,
    const float* __restrict__ fcb, float* __restrict__ outp)
{
  int b = blockIdx.x, t = threadIdx.x;
  __shared__ float row[512];
  __shared__ float y4[128];
  row[t] = y3[(size_t)b * 512 + t];
  row[t + 256] = y3[(size_t)b * 512 + t + 256];
  __syncthreads();
  if (t < 128) {
    float acc = l4b[t];
    const float* wr = l4w + (size_t)t * 512;
    for (int k = 0; k < 512; ++k) acc += row[k] * wr[k];
    const float scale = 1.0507009873554804934193349852946f;
    const float alpha = 1.6732632423543772848170429916717f;
    y4[t] = acc > 0.f ? scale * acc : scale * alpha * (__expf(acc) - 1.f);
  }
  __syncthreads();
  if (t < 2) {
    float acc = fcb[t];
    const float* wr = fcw + (size_t)t * 128;
    for (int k = 0; k < 128; ++k) acc += y4[k] * wr[k];
    outp[b * 2 + t] = 1.f / (1.f + __expf(-acc));
  }
}

extern "C" void kernel_launch(void* const* d_in, const int* in_sizes, int n_in,
                              void* d_out, int out_size, void* d_ws, size_t ws_size,
                              hipStream_t stream) {
  (void)in_sizes; (void)n_in; (void)out_size; (void)ws_size;
  const float* x     = (const float*)d_in[0];
  const float* Wih1  = (const float*)d_in[1];
  const float* Whh1  = (const float*)d_in[2];
  const float* bih1  = (const float*)d_in[3];
  const float* bhh1  = (const float*)d_in[4];
  const float* Wih21 = (const float*)d_in[5];
  const float* Whh21 = (const float*)d_in[6];
  const float* bih21 = (const float*)d_in[7];
  const float* bhh21 = (const float*)d_in[8];
  const float* Wih22 = (const float*)d_in[9];
  const float* Whh22 = (const float*)d_in[10];
  const float* bih22 = (const float*)d_in[11];
  const float* bhh22 = (const float*)d_in[12];
  const float* Wih31 = (const float*)d_in[13];
  const float* Whh31 = (const float*)d_in[14];
  const float* bih31 = (const float*)d_in[15];
  const float* bhh31 = (const float*)d_in[16];
  const float* Wih32 = (const float*)d_in[17];
  const float* Whh32 = (const float*)d_in[18];
  const float* bih32 = (const float*)d_in[19];
  const float* bhh32 = (const float*)d_in[20];
  const float* l4w   = (const float*)d_in[21];
  const float* l4b   = (const float*)d_in[22];
  const float* fcw   = (const float*)d_in[23];
  const float* fcb   = (const float*)d_in[24];

  char* ws = (char*)d_ws;
  __hip_bfloat16* xg     = (__hip_bfloat16*)(ws);               // 134217728 B
  __hip_bfloat16* y1     = (__hip_bfloat16*)(ws + 134217728);   // 33554432 B
  __hip_bfloat16* y2     = (__hip_bfloat16*)(ws + 167772160);   // 67108864 B
  float*          y3     = (float*)(ws + 234881024);            // 262144 B
  __hip_bfloat16* wihbf  = (__hip_bfloat16*)(ws + 235143168);   // 2097152 B
  float*          bsum   = (float*)(ws + 237240320);            // 20480 B
  float*          whht   = (float*)(ws + 237260800);            // 2621440 B
  float*          wihT13 = (float*)(ws + 239882240);            // 106496 B -> ~240.0 MB

  wconv<<<6780, 256, 0, stream>>>(Whh1, Whh21, Whh22, Whh31, Whh32,
                                  Wih21, Wih31, Wih32, Wih1, Wih22,
                                  bih1, bhh1, bih21, bhh21, bih22, bhh22,
                                  bih31, bhh31, bih32, bhh32,
                                  whht, wihbf, bsum, wihT13);

  ScanIO io;
  io.xg = nullptr; io.x = x;
  // layer 1 (fused D=13): x -> y1
  io.wihT = wihT13 + 0 * 13312;
  io.whht = whht + 0 * 131072; io.bs = bsum + 0 * 1024;
  io.yout = y1; io.ycols = 256; io.ycoloff = 0; io.y3out = nullptr; io.y3off = 0;
  lstm_scan2<true><<<dim3(128, 2), 1024, 0, stream>>>(io);
  // layer 22 (fused D=13): x -> y2 cols 256..511
  io.wihT = wihT13 + 1 * 13312;
  io.whht = whht + 2 * 131072; io.bs = bsum + 2 * 1024;
  io.yout = y2; io.ycols = 512; io.ycoloff = 256;
  lstm_scan2<true><<<dim3(128, 2), 1024, 0, stream>>>(io);
  // layer 21: y1 -> xg -> y2 cols 0..255
  projM<<<dim3(4, 512, 2), 256, 0, stream>>>(y1, 256, 256, wihbf + 0, bsum + 1 * 1024, xg);
  io.x = nullptr; io.wihT = nullptr; io.xg = xg;
  io.whht = whht + 1 * 131072; io.bs = bsum + 1 * 1024;
  io.yout = y2; io.ycols = 512; io.ycoloff = 0;
  lstm_scan2<false><<<dim3(128, 2), 1024, 0, stream>>>(io);
  // layer 31: y2 (K=512) -> xg -> y3 cols 0..255 (maxpool)
  projM<<<dim3(4, 512, 2), 256, 0, stream>>>(y2, 512, 512, wihbf + 262144, bsum + 3 * 1024, xg);
  io.whht = whht + 3 * 131072; io.bs = bsum + 3 * 1024;
  io.yout = nullptr; io.ycols = 0; io.ycoloff = 0; io.y3out = y3; io.y3off = 0;
  lstm_scan2<false><<<dim3(128, 2), 1024, 0, stream>>>(io);
  // layer 32: y21 (= y2 cols 0..255, K=256) -> xg -> y3 cols 256..511 (maxpool)
  projM<<<dim3(4, 512, 2), 256, 0, stream>>>(y2, 512, 256, wihbf + 786432, bsum + 4 * 1024, xg);
  io.whht = whht + 4 * 131072; io.bs = bsum + 4 * 1024;
  io.y3off = 256;
  lstm_scan2<false><<<dim3(128, 2), 1024, 0, stream>>>(io);
  // head
  head<<<128, 256, 0, stream>>>(y3, l4w, l4b, fcw, fcb, (float*)d_out);
}

// Round 4
// 2392.316 us; speedup vs baseline: 1.4262x; 1.3617x over previous
//
#include <hip/hip_runtime.h>
#include <hip/hip_bf16.h>

// Shapes: B=128, L=512, D=13, H=128, G=4H=512.
typedef __attribute__((ext_vector_type(8))) short bf16x8;
typedef __attribute__((ext_vector_type(4))) float f32x4;
typedef __attribute__((ext_vector_type(2))) float f32x2;

__device__ __forceinline__ float bfbits(unsigned short u) {
  unsigned int v = ((unsigned int)u) << 16;
  return __uint_as_float(v);
}
__device__ __forceinline__ float sigf(float x) { return 1.f / (1.f + __expf(-x)); }
__device__ __forceinline__ float tanhf_(float x) {
  x = fminf(15.f, fmaxf(-15.f, x));
  float t = __expf(2.f * x);
  return (t - 1.f) / (t + 1.f);
}

// ---------------------------------------------------------------------------
// Weight prep: Whh -> transposed fp32 whht[lay][d][k][j]; Wih(21/31/32) -> bf16
// for MFMA; bsum = bih + bhh; Wih(1/22) -> transposed fp32 for fused-D13 scan.
// ---------------------------------------------------------------------------
__global__ __launch_bounds__(256) void wconv(
    const float* whh0, const float* whh1, const float* whh2, const float* whh3, const float* whh4,
    const float* wi21, const float* wi31, const float* wi32,
    const float* wi1, const float* wi22,
    const float* bi0, const float* bh0, const float* bi1, const float* bh1,
    const float* bi2, const float* bh2, const float* bi3, const float* bh3,
    const float* bi4, const float* bh4,
    float* whht, __hip_bfloat16* wihbf, float* bsum, float* wihT13)
{
  int tid = blockIdx.x * 256 + threadIdx.x;
  if (tid < 5 * 131072) {                       // whht: [5][2][128][512]
    int lay = tid / 131072, r = tid % 131072;
    const float* src = lay == 0 ? whh0 : lay == 1 ? whh1 : lay == 2 ? whh2 : lay == 3 ? whh3 : whh4;
    int d = r >> 16;
    int k = (r >> 9) & 127;
    int j = r & 511;
    whht[tid] = src[((size_t)d * 512 + j) * 128 + k];   // Whh[d][j][k]
    return;
  }
  int t2 = tid - 5 * 131072;
  if (t2 < 1048576) {                           // wihbf: w21 | w31 | w32 (bf16)
    const float* src; int idx;
    if (t2 < 262144)      { src = wi21; idx = t2; }
    else if (t2 < 786432) { src = wi31; idx = t2 - 262144; }
    else                  { src = wi32; idx = t2 - 786432; }
    wihbf[t2] = __float2bfloat16(src[idx]);
    return;
  }
  int t3 = t2 - 1048576;
  if (t3 < 5120) {                              // bsum: [5][2][512]
    int lay = t3 >> 10, idx = t3 & 1023;
    const float* bi = lay == 0 ? bi0 : lay == 1 ? bi1 : lay == 2 ? bi2 : lay == 3 ? bi3 : bi4;
    const float* bh = lay == 0 ? bh0 : lay == 1 ? bh1 : lay == 2 ? bh2 : lay == 3 ? bh3 : bh4;
    bsum[t3] = bi[idx] + bh[idx];
    return;
  }
  int t4 = t3 - 5120;
  if (t4 < 26624) {                             // wihT13: [2][2][13][512]
    int lay = t4 / 13312, r = t4 % 13312;
    const float* src = lay == 0 ? wi1 : wi22;
    int d = r / 6656, rr = r % 6656;
    int k = rr / 512, j = rr % 512;
    wihT13[t4] = src[((size_t)d * 512 + j) * 13 + k];
  }
}

// ---------------------------------------------------------------------------
// bf16 MFMA projection GEMM (unchanged).
// ---------------------------------------------------------------------------
__global__ __launch_bounds__(256) void projM(
    const __hip_bfloat16* __restrict__ A, int lda, int K,
    const __hip_bfloat16* __restrict__ Bw,
    const float* __restrict__ bsum,
    __hip_bfloat16* __restrict__ out)
{
  int d = blockIdx.z;
  const __hip_bfloat16* Bp = Bw + (size_t)d * 512 * K;
  const float* bs = bsum + d * 512;
  __hip_bfloat16* op = out + (size_t)d * 65536 * 512;
  int m0 = blockIdx.y * 128, n0 = blockIdx.x * 128;
  __shared__ __align__(16) __hip_bfloat16 As[128][32];
  __shared__ __align__(16) __hip_bfloat16 Bs[128][32];
  int tid = threadIdx.x, w = tid >> 6, l = tid & 63;
  int wm = (w >> 1) * 64, wn = (w & 1) * 64;
  f32x4 acc[4][4];
#pragma unroll
  for (int mi = 0; mi < 4; ++mi)
#pragma unroll
    for (int ni = 0; ni < 4; ++ni) acc[mi][ni] = (f32x4){0.f, 0.f, 0.f, 0.f};
  int srow = tid >> 2, sc = tid & 3;
  for (int k0 = 0; k0 < K; k0 += 32) {
#pragma unroll
    for (int p = 0; p < 2; ++p) {
      int row = p * 64 + srow;
      int slot = sc ^ (row & 3);
      uint4 va = *(const uint4*)(A + (size_t)(m0 + row) * lda + k0 + sc * 8);
      *(uint4*)(&As[row][slot * 8]) = va;
      uint4 vb = *(const uint4*)(Bp + (size_t)(n0 + row) * K + k0 + sc * 8);
      *(uint4*)(&Bs[row][slot * 8]) = vb;
    }
    __syncthreads();
    bf16x8 af[4], bfr[4];
#pragma unroll
    for (int mi = 0; mi < 4; ++mi) {
      int row = wm + mi * 16 + (l & 15);
      int slot = (l >> 4) ^ (row & 3);
      af[mi] = *(const bf16x8*)(&As[row][slot * 8]);
    }
#pragma unroll
    for (int ni = 0; ni < 4; ++ni) {
      int row = wn + ni * 16 + (l & 15);
      int slot = (l >> 4) ^ (row & 3);
      bfr[ni] = *(const bf16x8*)(&Bs[row][slot * 8]);
    }
#pragma unroll
    for (int mi = 0; mi < 4; ++mi)
#pragma unroll
      for (int ni = 0; ni < 4; ++ni)
        acc[mi][ni] = __builtin_amdgcn_mfma_f32_16x16x32_bf16(af[mi], bfr[ni], acc[mi][ni], 0, 0, 0);
    __syncthreads();
  }
#pragma unroll
  for (int ni = 0; ni < 4; ++ni) {
    int col = n0 + wn + ni * 16 + (l & 15);
    float bsv = bs[col];
#pragma unroll
    for (int mi = 0; mi < 4; ++mi) {
#pragma unroll
      for (int q = 0; q < 4; ++q) {
        int row = m0 + wm + mi * 16 + (l >> 4) * 4 + q;
        op[(size_t)row * 512 + col] = __float2bfloat16(acc[mi][ni][q] + bsv);
      }
    }
  }
}

// ---------------------------------------------------------------------------
// LSTM scan v3 (fixed): block = (b, d), 1024 threads = (kq, gate-pair j2).
// Thread (kq, j2) computes gates j2 and j2+256 over k in [kq*32, kq*32+32):
//   - 32 v_pk_fma_f32 (2 MACs/instr) on weights PINNED in VGPRs via asm
//   - 8 ds_read_b128 broadcast h reads
// Partials reduced in p_lds[4][512]; cell (threads 0..127) exact fp32.
// ---------------------------------------------------------------------------
struct ScanIO {
  const __hip_bfloat16* xg;   // [2][B][L][512], used when !FUSE13
  const float* x;             // [B][L][13], used when FUSE13
  const float* wihT;          // [2][13][512], used when FUSE13
  const float* whht;          // [2][128][512]
  const float* bs;            // [2][512]
  __hip_bfloat16* yout; int ycols; int ycoloff;
  float* y3out; int y3off;
};

template<bool FUSE13>
__global__ __launch_bounds__(1024, 4) void lstm_scan3(ScanIO io)
{
  int b = blockIdx.x, d = blockIdx.y;
  int tid = threadIdx.x;
  int kq = tid >> 8, j2 = tid & 255;
  __shared__ __align__(16) float h_lds[128];
  __shared__ float p_lds[4][512];
  __shared__ float x_lds[FUSE13 ? 6656 : 4];

  // --- recurrent weights: 2 gate columns x 32 k, as 16+16 f32x2 pairs ------
  f32x2 w2a[16], w2b[16];
  {
    const float* wpa = io.whht + (size_t)d * 65536 + j2;
    const float* wpb = wpa + 256;
#pragma unroll
    for (int m = 0; m < 16; ++m) {
      int k = kq * 32 + 2 * m;
      w2a[m][0] = wpa[(size_t)k * 512];       w2a[m][1] = wpa[(size_t)(k + 1) * 512];
      w2b[m][0] = wpb[(size_t)k * 512];       w2b[m][1] = wpb[(size_t)(k + 1) * 512];
    }
  }
  // Pin in VGPRs: makes reload-rematerialization illegal.
#pragma unroll
  for (int m = 0; m < 16; ++m) {
    asm volatile("" : "+v"(w2a[m]));
    asm volatile("" : "+v"(w2b[m]));
  }

  // --- fused D=13 input weights, split across kq (4/3/3/3 dims) ------------
  int xk0 = (kq == 0) ? 0 : (3 * kq + 1);
  int xkn = (kq == 0) ? 4 : 3;
  float wxa[4], wxb[4];
  if (FUSE13) {
    const float* q = io.wihT + d * 6656 + j2;
#pragma unroll
    for (int m = 0; m < 4; ++m) {
      wxa[m] = (m < xkn) ? q[(xk0 + m) * 512] : 0.f;
      wxb[m] = (m < xkn) ? q[(xk0 + m) * 512 + 256] : 0.f;
    }
#pragma unroll
    for (int m = 0; m < 4; ++m) { asm volatile("" : "+v"(wxa[m])); asm volatile("" : "+v"(wxb[m])); }
    for (int i = tid; i < 6656; i += 1024) x_lds[i] = io.x[(size_t)b * 6656 + i];
  }
  float bias_a = 0.f, bias_b = 0.f;
  if (kq == 0) { bias_a = io.bs[d * 512 + j2]; bias_b = io.bs[d * 512 + j2 + 256]; }
  if (tid < 128) h_lds[tid] = 0.f;
  float c = 0.f, mreg = -1e30f;
  __hip_bfloat16* yp = io.yout ? io.yout + (size_t)b * 512 * io.ycols + io.ycoloff + d * 128 : (__hip_bfloat16*)0;
  const __hip_bfloat16* xp = FUSE13 ? (const __hip_bfloat16*)0 : io.xg + ((size_t)d * 128 + b) * 262144;
  __syncthreads();

  unsigned short xra = 0, xrb = 0;
  if (!FUSE13 && kq == 0) {
    int tt0 = d ? 511 : 0;
    xra = *(const unsigned short*)(xp + (size_t)tt0 * 512 + j2);
    xrb = *(const unsigned short*)(xp + (size_t)tt0 * 512 + j2 + 256);
  }
  for (int t = 0; t < 512; ++t) {
    int tt = d ? 511 - t : t;
    unsigned short xna = 0, xnb = 0;
    if (!FUSE13 && kq == 0) {
      int tn = (t + 1 < 512) ? t + 1 : 511;
      int ttn = d ? 511 - tn : tn;
      xna = *(const unsigned short*)(xp + (size_t)ttn * 512 + j2);          // prefetch
      xnb = *(const unsigned short*)(xp + (size_t)ttn * 512 + j2 + 256);
    }
    float xa = bias_a, xb = bias_b;
    if (FUSE13) {
      const float* xr = &x_lds[tt * 13 + xk0];
#pragma unroll
      for (int m = 0; m < 4; ++m) {
        if (m < xkn) { xa += xr[m] * wxa[m]; xb += xr[m] * wxb[m]; }
      }
    } else if (kq == 0) {
      xa += bfbits(xra); xb += bfbits(xrb);
    }
    f32x2 aa = {0.f, 0.f}, ab = {0.f, 0.f};
    const f32x4* h4 = (const f32x4*)&h_lds[kq * 32];
#pragma unroll
    for (int mm = 0; mm < 8; ++mm) {
      f32x4 hv = h4[mm];
      f32x2 hlo = __builtin_shufflevector(hv, hv, 0, 1);
      f32x2 hhi = __builtin_shufflevector(hv, hv, 2, 3);
      asm("v_pk_fma_f32 %0, %1, %2, %0" : "+v"(aa) : "v"(w2a[2 * mm]), "v"(hlo));
      asm("v_pk_fma_f32 %0, %1, %2, %0" : "+v"(ab) : "v"(w2b[2 * mm]), "v"(hlo));
      asm("v_pk_fma_f32 %0, %1, %2, %0" : "+v"(aa) : "v"(w2a[2 * mm + 1]), "v"(hhi));
      asm("v_pk_fma_f32 %0, %1, %2, %0" : "+v"(ab) : "v"(w2b[2 * mm + 1]), "v"(hhi));
    }
    p_lds[kq][j2]       = aa[0] + aa[1] + xa;
    p_lds[kq][j2 + 256] = ab[0] + ab[1] + xb;
    __syncthreads();
    if (tid < 128) {
      float gi = p_lds[0][tid]       + p_lds[1][tid]       + p_lds[2][tid]       + p_lds[3][tid];
      float gf = p_lds[0][tid + 128] + p_lds[1][tid + 128] + p_lds[2][tid + 128] + p_lds[3][tid + 128];
      float gg = p_lds[0][tid + 256] + p_lds[1][tid + 256] + p_lds[2][tid + 256] + p_lds[3][tid + 256];
      float go = p_lds[0][tid + 384] + p_lds[1][tid + 384] + p_lds[2][tid + 384] + p_lds[3][tid + 384];
      c = sigf(gf) * c + sigf(gi) * tanhf_(gg);
      float h = sigf(go) * tanhf_(c);
      h_lds[tid] = h;
      if (yp) yp[(size_t)tt * io.ycols + tid] = __float2bfloat16(h);
      else mreg = fmaxf(mreg, h);
    }
    __syncthreads();
    xra = xna; xrb = xnb;
  }
  // FIX(R3): direction offset d*128 was missing -> both dirs raced into the
  // same columns and half of y3 stayed unwritten. Restored from v2.
  if (!yp && tid < 128) io.y3out[(size_t)b * 512 + io.y3off + d * 128 + tid] = mreg;
}

// ---------------------------------------------------------------------------
// Head: y4 = selu(y3 @ l4w^T + l4b); out = sigmoid(y4 @ fcw^T + fcb).
// ---------------------------------------------------------------------------
__global__ __launch_bounds__(256) void head(
    const float* __restrict__ y3, const float* __restrict__ l4w,
    const float* __restrict__ l4b, const float* __restrict__ fcw,
    const float* __restrict__ fcb, float* __restrict__ outp)
{
  int b = blockIdx.x, t = threadIdx.x;
  __shared__ float row[512];
  __shared__ float y4[128];
  row[t] = y3[(size_t)b * 512 + t];
  row[t + 256] = y3[(size_t)b * 512 + t + 256];
  __syncthreads();
  if (t < 128) {
    float acc = l4b[t];
    const float* wr = l4w + (size_t)t * 512;
    for (int k = 0; k < 512; ++k) acc += row[k] * wr[k];
    const float scale = 1.0507009873554804934193349852946f;
    const float alpha = 1.6732632423543772848170429916717f;
    y4[t] = acc > 0.f ? scale * acc : scale * alpha * (__expf(acc) - 1.f);
  }
  __syncthreads();
  if (t < 2) {
    float acc = fcb[t];
    const float* wr = fcw + (size_t)t * 128;
    for (int k = 0; k < 128; ++k) acc += y4[k] * wr[k];
    outp[b * 2 + t] = 1.f / (1.f + __expf(-acc));
  }
}

extern "C" void kernel_launch(void* const* d_in, const int* in_sizes, int n_in,
                              void* d_out, int out_size, void* d_ws, size_t ws_size,
                              hipStream_t stream) {
  (void)in_sizes; (void)n_in; (void)out_size; (void)ws_size;
  const float* x     = (const float*)d_in[0];
  const float* Wih1  = (const float*)d_in[1];
  const float* Whh1  = (const float*)d_in[2];
  const float* bih1  = (const float*)d_in[3];
  const float* bhh1  = (const float*)d_in[4];
  const float* Wih21 = (const float*)d_in[5];
  const float* Whh21 = (const float*)d_in[6];
  const float* bih21 = (const float*)d_in[7];
  const float* bhh21 = (const float*)d_in[8];
  const float* Wih22 = (const float*)d_in[9];
  const float* Whh22 = (const float*)d_in[10];
  const float* bih22 = (const float*)d_in[11];
  const float* bhh22 = (const float*)d_in[12];
  const float* Wih31 = (const float*)d_in[13];
  const float* Whh31 = (const float*)d_in[14];
  const float* bih31 = (const float*)d_in[15];
  const float* bhh31 = (const float*)d_in[16];
  const float* Wih32 = (const float*)d_in[17];
  const float* Whh32 = (const float*)d_in[18];
  const float* bih32 = (const float*)d_in[19];
  const float* bhh32 = (const float*)d_in[20];
  const float* l4w   = (const float*)d_in[21];
  const float* l4b   = (const float*)d_in[22];
  const float* fcw   = (const float*)d_in[23];
  const float* fcb   = (const float*)d_in[24];

  char* ws = (char*)d_ws;
  __hip_bfloat16* xg     = (__hip_bfloat16*)(ws);               // 134217728 B
  __hip_bfloat16* y1     = (__hip_bfloat16*)(ws + 134217728);   // 33554432 B
  __hip_bfloat16* y2     = (__hip_bfloat16*)(ws + 167772160);   // 67108864 B
  float*          y3     = (float*)(ws + 234881024);            // 262144 B
  __hip_bfloat16* wihbf  = (__hip_bfloat16*)(ws + 235143168);   // 2097152 B
  float*          bsum   = (float*)(ws + 237240320);            // 20480 B
  float*          whht   = (float*)(ws + 237260800);            // 2621440 B
  float*          wihT13 = (float*)(ws + 239882240);            // 106496 B -> ~240.0 MB

  wconv<<<6780, 256, 0, stream>>>(Whh1, Whh21, Whh22, Whh31, Whh32,
                                  Wih21, Wih31, Wih32, Wih1, Wih22,
                                  bih1, bhh1, bih21, bhh21, bih22, bhh22,
                                  bih31, bhh31, bih32, bhh32,
                                  whht, wihbf, bsum, wihT13);

  ScanIO io;
  io.xg = nullptr; io.x = x;
  // layer 1 (fused D=13): x -> y1
  io.wihT = wihT13 + 0 * 13312;
  io.whht = whht + 0 * 131072; io.bs = bsum + 0 * 1024;
  io.yout = y1; io.ycols = 256; io.ycoloff = 0; io.y3out = nullptr; io.y3off = 0;
  lstm_scan3<true><<<dim3(128, 2), 1024, 0, stream>>>(io);
  // layer 22 (fused D=13): x -> y2 cols 256..511
  io.wihT = wihT13 + 1 * 13312;
  io.whht = whht + 2 * 131072; io.bs = bsum + 2 * 1024;
  io.yout = y2; io.ycols = 512; io.ycoloff = 256;
  lstm_scan3<true><<<dim3(128, 2), 1024, 0, stream>>>(io);
  // layer 21: y1 -> xg -> y2 cols 0..255
  projM<<<dim3(4, 512, 2), 256, 0, stream>>>(y1, 256, 256, wihbf + 0, bsum + 1 * 1024, xg);
  io.x = nullptr; io.wihT = nullptr; io.xg = xg;
  io.whht = whht + 1 * 131072; io.bs = bsum + 1 * 1024;
  io.yout = y2; io.ycols = 512; io.ycoloff = 0;
  lstm_scan3<false><<<dim3(128, 2), 1024, 0, stream>>>(io);
  // layer 31: y2 (K=512) -> xg -> y3 cols 0..255 (maxpool)
  projM<<<dim3(4, 512, 2), 256, 0, stream>>>(y2, 512, 512, wihbf + 262144, bsum + 3 * 1024, xg);
  io.whht = whht + 3 * 131072; io.bs = bsum + 3 * 1024;
  io.yout = nullptr; io.ycols = 0; io.ycoloff = 0; io.y3out = y3; io.y3off = 0;
  lstm_scan3<false><<<dim3(128, 2), 1024, 0, stream>>>(io);
  // layer 32: y21 (= y2 cols 0..255, K=256) -> xg -> y3 cols 256..511 (maxpool)
  projM<<<dim3(4, 512, 2), 256, 0, stream>>>(y2, 512, 256, wihbf + 786432, bsum + 4 * 1024, xg);
  io.whht = whht + 4 * 131072; io.bs = bsum + 4 * 1024;
  io.y3off = 256;
  lstm_scan3<false><<<dim3(128, 2), 1024, 0, stream>>>(io);
  // head
  head<<<128, 256, 0, stream>>>(y3, l4w, l4b, fcw, fcb, (float*)d_out);
}